// Round 20
// baseline (163.101 us; speedup 1.0000x reference)
//
#include <hip/hip_runtime.h>

typedef _Float16 v8h  __attribute__((ext_vector_type(8)));
typedef _Float16 v4h  __attribute__((ext_vector_type(4)));
typedef __fp16   fp16x2 __attribute__((ext_vector_type(2)));
typedef float    v4f  __attribute__((ext_vector_type(4)));
typedef float    v16f __attribute__((ext_vector_type(16)));

#define HH 192
#define WW 192
#define PIX (HH*WW)
#define PITCH 528    // 33 x 16B slots, 33 coprime 32 -> conflict-free
#define GPITCH 1168  // 73 x 16B slots, 73 mod 32 = 9, coprime -> conflict-free

// ---------------- ws layout (bytes) ----------------
static const size_t OFF_FEAT  = 0;
static const size_t OFF_G     = 4718592;
static const size_t OFF_QTAB  = 23592960;
static const size_t OFF_W0P   = 27787264;  // 147456 fp16 = 294912 B (32x32 frag)
static const size_t OFF_W1P   = 28082176;
static const size_t OFF_W2P   = 28213248;
static const size_t OFF_W3P   = 28344320;
static const size_t OFF_W4P32 = 28475392;  // 16ks*512 fp16 = 16384 B (R11 pack)
static const size_t OFF_WTP   = 28491776;  // 1024 fp16 = 2048 B

// packed relu->fp16 via builtin (relu in f32, then RTZ pack cvt)
__device__ __forceinline__ unsigned pkrelu(float f0, float f1) {
  union { fp16x2 h; unsigned u; } cv;
  cv.h = __builtin_amdgcn_cvt_pkrtz(fmaxf(f0, 0.f), fmaxf(f1, 0.f));
  return cv.u;
}

// ---------------- prep bodies ----------------
// w0 pack, 32x32x16 fragment layout, K=576 (im2col packed-k), N=256.
// dst[((ct*36+ks)*64+l)*8+j] = w0[row(k)*256 + ct*32+(l&31)],
// k = ks*16+(l>>5)*8+j, row = (k&63)*9 + (k>>6).
__device__ __forceinline__ void pack32g_body(const float* __restrict__ w0,
                                             _Float16* __restrict__ dst, int gid) {
  int j  = gid & 7;
  int l  = (gid >> 3) & 63;
  int cks = gid >> 9;               // ct*36 + ks, 0..287
  int ks = cks % 36;
  int ct = cks / 36;
  int k = ks * 16 + ((l >> 5) << 3) + j;
  int row = (k & 63) * 9 + (k >> 6);
  int col = ct * 32 + (l & 31);
  dst[gid] = (_Float16)w0[row * 256 + col];
}

__device__ __forceinline__ void pack32_body(const float* __restrict__ src,
                                            _Float16* __restrict__ dst, int gid) {
  int j  = gid & 7;
  int l  = (gid >> 3) & 63;
  int ks = (gid >> 9) & 15;
  int ct = gid >> 13;
  int k = ks * 16 + ((l >> 5) << 3) + j;
  int n = ct * 32 + (l & 31);
  dst[gid] = (_Float16)src[k * 256 + n];
}

// ---------------- fused prep ----------------
// [0,1152) conv 8ch/thread | [1152,1408) qsetup | [1408,1984) w0p (pack32g) |
// [1984,2240) w1p | [2240,2496) w2p | [2496,2752) w3p |
// [2752,2784) w4p32 (permuted rows, cols padded to 32) | [2784,2788) wtp
__global__ __launch_bounds__(256) void k_prep(
    const float* __restrict__ inp, const float* __restrict__ coord,
    const float* __restrict__ enc_w, const float* __restrict__ enc_b,
    const float* __restrict__ w0, const float* __restrict__ w1,
    const float* __restrict__ w2, const float* __restrict__ w3,
    const float* __restrict__ w4,
    _Float16* __restrict__ feat, float4* __restrict__ qtab,
    _Float16* __restrict__ w0p, _Float16* __restrict__ w1p,
    _Float16* __restrict__ w2p, _Float16* __restrict__ w3p,
    _Float16* __restrict__ w4p32, _Float16* __restrict__ wtp) {
  int blk = blockIdx.x, t = threadIdx.x;
  if (blk < 1152) {
    __shared__ float sew[27 * 64];
    __shared__ float seb[64];
    for (int i = t; i < 1728; i += 256) {
      int tap = i >> 6, c = i & 63;
      sew[i] = enc_w[c * 27 + tap];
    }
    if (t < 64) seb[t] = enc_b[t];
    __syncthreads();
    int gid = blk * 256 + t;
    int p = gid >> 3, c8 = (gid & 7) * 8;
    int y = p / WW, x = p - y * WW;
    float a[8];
    #pragma unroll
    for (int j = 0; j < 8; ++j) a[j] = seb[c8 + j];
    #pragma unroll
    for (int ci = 0; ci < 3; ++ci) {
      #pragma unroll
      for (int dy = 0; dy < 3; ++dy) {
        #pragma unroll
        for (int dx = 0; dx < 3; ++dx) {
          int yy = y + dy - 1, xx = x + dx - 1;
          float v = (yy >= 0 && yy < HH && xx >= 0 && xx < WW)
                        ? inp[ci * PIX + yy * WW + xx] : 0.f;
          int tap = ci * 9 + dy * 3 + dx;
          v4f wlo = *(const v4f*)(sew + tap * 64 + c8);
          v4f whi = *(const v4f*)(sew + tap * 64 + c8 + 4);
          a[0] += v * wlo[0]; a[1] += v * wlo[1];
          a[2] += v * wlo[2]; a[3] += v * wlo[3];
          a[4] += v * whi[0]; a[5] += v * whi[1];
          a[6] += v * whi[2]; a[7] += v * whi[3];
        }
      }
    }
    v8h o;
    #pragma unroll
    for (int j = 0; j < 8; ++j) o[j] = (_Float16)a[j];
    *(v8h*)(feat + p * 64 + c8) = o;
  } else if (blk < 1408) {
    int q = (blk - 1152) * 256 + t;
    float cy = coord[q * 2 + 0], cx = coord[q * 2 + 1];
    const float eps = 1e-6f;
    const float rad = (float)(1.0 / 192.0);
    const float CLO = (float)(-1.0 + 1e-6);
    const float CHI = (float)(1.0 - 1e-6);
    const float S2  = (float)(2.0 / 192.0);
    float ry[4], rx[4], ar[4];
    int   li[4];
    #pragma unroll
    for (int k = 0; k < 4; ++k) {
      float oy = (k < 2) ? -rad : rad;
      float ox = (k & 1) ? rad : -rad;
      float cey = __fadd_rn(__fadd_rn(cy, oy), eps);
      float cex = __fadd_rn(__fadd_rn(cx, ox), eps);
      cey = fminf(fmaxf(cey, CLO), CHI);
      cex = fminf(fmaxf(cex, CLO), CHI);
      float ty = __fmul_rn(__fsub_rn(__fmul_rn(__fadd_rn(cey, 1.0f), 192.0f), 1.0f), 0.5f);
      float tx = __fmul_rn(__fsub_rn(__fmul_rn(__fadd_rn(cex, 1.0f), 192.0f), 1.0f), 0.5f);
      float fy = fminf(fmaxf(rintf(ty), 0.f), 191.f);
      float fx = fminf(fmaxf(rintf(tx), 0.f), 191.f);
      float qy = __fsub_rn(__fmul_rn(__fadd_rn(fy, 0.5f), S2), 1.0f);
      float qx = __fsub_rn(__fmul_rn(__fadd_rn(fx, 0.5f), S2), 1.0f);
      ry[k] = __fmul_rn(__fsub_rn(cy, qy), 192.0f);
      rx[k] = __fmul_rn(__fsub_rn(cx, qx), 192.0f);
      ar[k] = fabsf(ry[k] * rx[k]) + 1e-9f;
      li[k] = (int)fy * WW + (int)fx;
    }
    float tot = ar[0] + ar[1] + ar[2] + ar[3];
    #pragma unroll
    for (int k = 0; k < 4; ++k) {
      float wk = ar[3 - k] / tot;
      qtab[q * 4 + k] = make_float4(__int_as_float(li[k]), ry[k], rx[k], wk);
    }
  } else if (blk < 1984) {
    pack32g_body(w0, w0p, (blk - 1408) * 256 + t);
  } else if (blk < 2240) {
    pack32_body(w1, w1p, (blk - 1984) * 256 + t);
  } else if (blk < 2496) {
    pack32_body(w2, w2p, (blk - 2240) * 256 + t);
  } else if (blk < 2752) {
    pack32_body(w3, w3p, (blk - 2496) * 256 + t);
  } else if (blk < 2784) {
    // w4p32: 256x3 -> PERMUTED rows (D-fragment order), cols padded to 32
    int gid = (blk - 2752) * 256 + t;       // 0..8191
    int j  = gid & 7;
    int l  = (gid >> 3) & 63;
    int ks = gid >> 9;                      // 0..15
    int k = ks * 16 + ((l >> 5) << 2) + (j & 3) + ((j >> 2) << 3);
    int n = l & 31;
    w4p32[gid] = (n < 3) ? (_Float16)w4[k * 3 + n] : (_Float16)0.f;
  } else {
    int i = (blk - 2784) * 256 + t;
    if (i < 1024) {
      int col = i & 7, j = (i >> 3) & 3, ch = i >> 5;
      wtp[i] = (_Float16)w0[(576 + j) * 256 + ch * 8 + col];
    }
  }
}

// ---------------- G-GEMM: M=64 pixels/block, 32x32x16, PITCH-affine ----------
// Per wave: cols [wv*64, wv*64+64) as 2 col-tiles; 2 sample-tiles of 32.
// acc 64 AGPR, bias via C-in, weight frags reused 2x, conflict-free LDS.
__global__ __launch_bounds__(256) void k_ggemm(const _Float16* __restrict__ feat,
    const _Float16* __restrict__ w0g, const float* __restrict__ b0,
    _Float16* __restrict__ G) {
  __shared__ __align__(16) char lds[64 * GPITCH];
  int t = threadIdx.x, blk = blockIdx.x;
  int lane = t & 63, wv = t >> 6;
  int sl = lane & 31, kg = lane >> 5;
  // stage im2col: 64 rows x 9 nbrs x 128B (72 x 16B chunks per row)
  #pragma unroll
  for (int it = 0; it < 18; ++it) {
    int flat = it * 256 + t;          // 0..4607
    int r = flat / 72;
    int rem = flat - r * 72;
    int n = rem >> 3, ch = rem & 7;
    int p = blk * 64 + r;
    int y = p / WW, x = p - y * WW;
    int ni = n / 3;
    int yy = y + ni - 1, xx = x + (n - ni * 3) - 1;
    v8h v = {};
    if (yy >= 0 && yy < HH && xx >= 0 && xx < WW)
      v = *(const v8h*)(feat + (yy * WW + xx) * 64 + ch * 8);
    *(v8h*)(lds + r * GPITCH + n * 128 + ch * 16) = v;
  }
  __syncthreads();
  v16f acc[2][2];
  #pragma unroll
  for (int c = 0; c < 2; ++c) {
    #pragma unroll
    for (int q = 0; q < 4; ++q) {
      float4 bb = *(const float4*)(b0 + wv * 64 + c * 32 + q * 8 + kg * 4);
      #pragma unroll
      for (int st = 0; st < 2; ++st) {
        acc[st][c][q * 4 + 0] = bb.x;
        acc[st][c][q * 4 + 1] = bb.y;
        acc[st][c][q * 4 + 2] = bb.z;
        acc[st][c][q * 4 + 3] = bb.w;
      }
    }
  }
  const char* bbase = lds + sl * GPITCH + kg * 16;
  const _Float16* wb0 = w0g + (size_t)((wv * 2 + 0) * 36) * 512 + lane * 8;
  const _Float16* wb1 = w0g + (size_t)((wv * 2 + 1) * 36) * 512 + lane * 8;
  #pragma unroll
  for (int ks = 0; ks < 36; ++ks) {
    v8h afr0 = *(const v8h*)(wb0 + ks * 512);
    v8h afr1 = *(const v8h*)(wb1 + ks * 512);
    v8h bfr0 = *(const v8h*)(bbase + ks * 32);
    v8h bfr1 = *(const v8h*)(bbase + 32 * GPITCH + ks * 32);
    acc[0][0] = __builtin_amdgcn_mfma_f32_32x32x16_f16(afr0, bfr0, acc[0][0], 0, 0, 0);
    acc[0][1] = __builtin_amdgcn_mfma_f32_32x32x16_f16(afr1, bfr0, acc[0][1], 0, 0, 0);
    acc[1][0] = __builtin_amdgcn_mfma_f32_32x32x16_f16(afr0, bfr1, acc[1][0], 0, 0, 0);
    acc[1][1] = __builtin_amdgcn_mfma_f32_32x32x16_f16(afr1, bfr1, acc[1][1], 0, 0, 0);
  }
  __syncthreads();   // staging reads done; reuse lds for output transpose
  // epilogue (no relu, RN converts): D col=lane&31 (sample),
  // row = (reg&3) + 8*(reg>>2) + 4*kg
  #pragma unroll
  for (int c = 0; c < 2; ++c) {
    #pragma unroll
    for (int q = 0; q < 4; ++q) {
      int n0 = wv * 64 + c * 32 + q * 8 + kg * 4;
      #pragma unroll
      for (int st = 0; st < 2; ++st) {
        int s = st * 32 + sl;
        v4h h;
        h[0] = (_Float16)acc[st][c][q * 4 + 0];
        h[1] = (_Float16)acc[st][c][q * 4 + 1];
        h[2] = (_Float16)acc[st][c][q * 4 + 2];
        h[3] = (_Float16)acc[st][c][q * 4 + 3];
        *(v4h*)(lds + s * PITCH + n0 * 2) = h;
      }
    }
  }
  __syncthreads();
  // coalesced store: 64 rows x 512B
  #pragma unroll
  for (int i = 0; i < 8; ++i) {
    int ci = i * 256 + t;
    int m = ci >> 5, sl2 = ci & 31;
    v8h v = *(const v8h*)(lds + m * PITCH + sl2 * 16);
    *(v8h*)(G + (size_t)(blk * 64 + m) * 256 + sl2 * 8) = v;
  }
}

// ------- hidden layer (256->256), relu, single buffer, 32x32x16 -------
__device__ __forceinline__ void layer256w(char* buf,
    const _Float16* __restrict__ wp, const float* __restrict__ bias,
    int lane, int wv) {
  int sl = lane & 31;
  int kg = lane >> 5;
  v16f acc[4][2];
  #pragma unroll
  for (int c = 0; c < 2; ++c) {
    #pragma unroll
    for (int q = 0; q < 4; ++q) {
      float4 bb = *(const float4*)(bias + wv * 64 + c * 32 + q * 8 + kg * 4);
      #pragma unroll
      for (int st = 0; st < 4; ++st) {
        acc[st][c][q * 4 + 0] = bb.x;
        acc[st][c][q * 4 + 1] = bb.y;
        acc[st][c][q * 4 + 2] = bb.z;
        acc[st][c][q * 4 + 3] = bb.w;
      }
    }
  }
  const _Float16* wbase = wp + (size_t)(wv * 2) * 16 * 512 + lane * 8;
  const char* bbase = buf + sl * PITCH + kg * 16;
  #pragma unroll
  for (int ks = 0; ks < 16; ++ks) {
    v8h afr[2], bfr[4];
    afr[0] = *(const v8h*)(wbase + ks * 512);
    afr[1] = *(const v8h*)(wbase + (16 + ks) * 512);
    #pragma unroll
    for (int st = 0; st < 4; ++st)
      bfr[st] = *(const v8h*)(bbase + st * (32 * PITCH) + ks * 32);
    #pragma unroll
    for (int st = 0; st < 4; ++st)
      #pragma unroll
      for (int c = 0; c < 2; ++c)
        acc[st][c] = __builtin_amdgcn_mfma_f32_32x32x16_f16(afr[c], bfr[st], acc[st][c], 0, 0, 0);
  }
  __syncthreads();
  // D layout (32x32): col=lane&31 (sample), row=(reg&3)+8*(reg>>2)+4*(lane>>5)
  #pragma unroll
  for (int c = 0; c < 2; ++c) {
    #pragma unroll
    for (int q = 0; q < 4; ++q) {
      int n0 = wv * 64 + c * 32 + q * 8 + kg * 4;
      #pragma unroll
      for (int st = 0; st < 4; ++st) {
        int s = st * 32 + sl;
        uint2 hv;
        hv.x = pkrelu(acc[st][c][q * 4 + 0], acc[st][c][q * 4 + 1]);
        hv.y = pkrelu(acc[st][c][q * 4 + 2], acc[st][c][q * 4 + 3]);
        *(uint2*)(buf + s * PITCH + n0 * 2) = hv;
      }
    }
  }
  __syncthreads();
}

// ------- layer 3 + fused L4: acc feeds L4's B-operand directly -------
__device__ __forceinline__ void layer3_fused(char* buf,
    const _Float16* __restrict__ wp, const float* __restrict__ bias,
    const _Float16* __restrict__ w4p32, const float* __restrict__ b4,
    const float4* __restrict__ qtab, float* __restrict__ out,
    int lane, int wv, int blk, int t) {
  int sl = lane & 31;
  int kg = lane >> 5;
  v16f acc[4][2];
  #pragma unroll
  for (int c = 0; c < 2; ++c) {
    #pragma unroll
    for (int q = 0; q < 4; ++q) {
      float4 bb = *(const float4*)(bias + wv * 64 + c * 32 + q * 8 + kg * 4);
      #pragma unroll
      for (int st = 0; st < 4; ++st) {
        acc[st][c][q * 4 + 0] = bb.x;
        acc[st][c][q * 4 + 1] = bb.y;
        acc[st][c][q * 4 + 2] = bb.z;
        acc[st][c][q * 4 + 3] = bb.w;
      }
    }
  }
  const _Float16* wbase = wp + (size_t)(wv * 2) * 16 * 512 + lane * 8;
  const char* bbase = buf + sl * PITCH + kg * 16;
  #pragma unroll
  for (int ks = 0; ks < 16; ++ks) {
    v8h afr[2], bfr[4];
    afr[0] = *(const v8h*)(wbase + ks * 512);
    afr[1] = *(const v8h*)(wbase + (16 + ks) * 512);
    #pragma unroll
    for (int st = 0; st < 4; ++st)
      bfr[st] = *(const v8h*)(bbase + st * (32 * PITCH) + ks * 32);
    #pragma unroll
    for (int st = 0; st < 4; ++st)
      #pragma unroll
      for (int c = 0; c < 2; ++c)
        acc[st][c] = __builtin_amdgcn_mfma_f32_32x32x16_f16(afr[c], bfr[st], acc[st][c], 0, 0, 0);
  }
  __syncthreads();   // all reads of buf done -> buf reusable for partials
  float4* pb = (float4*)buf;
  #pragma unroll
  for (int st = 0; st < 4; ++st) {
    v16f a4 = {};
    #pragma unroll
    for (int ksl = 0; ksl < 4; ++ksl) {
      const v16f& a = acc[st][ksl >> 1];
      int base = 8 * (ksl & 1);
      union { unsigned u[4]; v8h h; } bb;
      bb.u[0] = pkrelu(a[base + 0], a[base + 1]);
      bb.u[1] = pkrelu(a[base + 2], a[base + 3]);
      bb.u[2] = pkrelu(a[base + 4], a[base + 5]);
      bb.u[3] = pkrelu(a[base + 6], a[base + 7]);
      v8h afr = *(const v8h*)(w4p32 + (size_t)(wv * 4 + ksl) * 512 + lane * 8);
      a4 = __builtin_amdgcn_mfma_f32_32x32x16_f16(afr, bb.h, a4, 0, 0, 0);
    }
    if (kg == 0) {
      pb[wv * 128 + st * 32 + sl] = make_float4(a4[0], a4[1], a4[2], 0.f);
    }
  }
  __syncthreads();
  if (t < 96) {
    int ql = t / 3, ch = t - ql * 3;
    float bch = b4[ch];
    float sum = 0.f;
    #pragma unroll
    for (int k = 0; k < 4; ++k) {
      int s_local = ql * 4 + k;
      float wk = qtab[blk * 128 + s_local].w;
      float pred = bch;
      #pragma unroll
      for (int w = 0; w < 4; ++w)
        pred += ((const float*)&pb[w * 128 + s_local])[ch];
      sum += wk * pred;
    }
    out[(blk * 32 + ql) * 3 + ch] = sum;
  }
}

// ---------------- fused MLP over 128 samples/block -------------
__global__ __launch_bounds__(256, 2) void k_mlp(
    const _Float16* __restrict__ G, const float4* __restrict__ qtab,
    const float* __restrict__ cell, const _Float16* __restrict__ wtp,
    const _Float16* __restrict__ w1p, const _Float16* __restrict__ w2p,
    const _Float16* __restrict__ w3p, const _Float16* __restrict__ w4p32,
    const float* __restrict__ b1, const float* __restrict__ b2,
    const float* __restrict__ b3, const float* __restrict__ b4,
    float* __restrict__ out) {
  __shared__ __align__(16) char buf[128 * PITCH];
  int t = threadIdx.x, blk = blockIdx.x;
  int lane = t & 63, wv = t >> 6;
  // ---- phase 0: h1 = relu(G[pix] + tail-terms) -> buf ----
  {
    int ch = t & 31;
    int r8 = t >> 5;
    const _Float16* wtb = wtp + ch * 32;
    v8h wt0 = *(const v8h*)(wtb);
    v8h wt1 = *(const v8h*)(wtb + 8);
    v8h wt2 = *(const v8h*)(wtb + 16);
    v8h wt3 = *(const v8h*)(wtb + 24);
    #pragma unroll
    for (int g = 0; g < 16; ++g) {
      int r = g * 8 + r8;
      int s = blk * 128 + r;
      float4 qe = qtab[s];
      int lin = __float_as_int(qe.x);
      float rel0 = qe.y, rel1 = qe.z;
      int q = s >> 2;
      float rc0 = cell[q * 2 + 0] * 192.f, rc1 = cell[q * 2 + 1] * 192.f;
      v8h gv = *(const v8h*)(G + (size_t)lin * 256 + ch * 8);
      float vv[8];
      #pragma unroll
      for (int i = 0; i < 8; ++i)
        vv[i] = (float)gv[i] + rel0 * (float)wt0[i] + rel1 * (float)wt1[i]
              + rc0 * (float)wt2[i] + rc1 * (float)wt3[i];
      uint4 hv;
      hv.x = pkrelu(vv[0], vv[1]);
      hv.y = pkrelu(vv[2], vv[3]);
      hv.z = pkrelu(vv[4], vv[5]);
      hv.w = pkrelu(vv[6], vv[7]);
      *(uint4*)(buf + r * PITCH + ch * 16) = hv;
    }
  }
  __syncthreads();
  layer256w(buf, w1p, b1, lane, wv);
  layer256w(buf, w2p, b2, lane, wv);
  layer3_fused(buf, w3p, b3, w4p32, b4, qtab, out, lane, wv, blk, t);
}

extern "C" void kernel_launch(void* const* d_in, const int* in_sizes, int n_in,
                              void* d_out, int out_size, void* d_ws, size_t ws_size,
                              hipStream_t stream) {
  const float* inp   = (const float*)d_in[0];
  const float* coord = (const float*)d_in[1];
  const float* cell  = (const float*)d_in[2];
  const float* enc_w = (const float*)d_in[3];
  const float* enc_b = (const float*)d_in[4];
  const float* w0 = (const float*)d_in[5];
  const float* b0 = (const float*)d_in[6];
  const float* w1 = (const float*)d_in[7];
  const float* b1 = (const float*)d_in[8];
  const float* w2 = (const float*)d_in[9];
  const float* b2 = (const float*)d_in[10];
  const float* w3 = (const float*)d_in[11];
  const float* b3 = (const float*)d_in[12];
  const float* w4 = (const float*)d_in[13];
  const float* b4 = (const float*)d_in[14];
  char* ws = (char*)d_ws;
  _Float16* feat  = (_Float16*)(ws + OFF_FEAT);
  _Float16* G     = (_Float16*)(ws + OFF_G);
  float4*   qtab  = (float4*)(ws + OFF_QTAB);
  _Float16* w0p   = (_Float16*)(ws + OFF_W0P);
  _Float16* w1p   = (_Float16*)(ws + OFF_W1P);
  _Float16* w2p   = (_Float16*)(ws + OFF_W2P);
  _Float16* w3p   = (_Float16*)(ws + OFF_W3P);
  _Float16* w4p32 = (_Float16*)(ws + OFF_W4P32);
  _Float16* wtp   = (_Float16*)(ws + OFF_WTP);

  k_prep<<<2788, 256, 0, stream>>>(inp, coord, enc_w, enc_b, w0, w1, w2, w3, w4,
                                   feat, qtab, w0p, w1p, w2p, w3p, w4p32, wtp);
  k_ggemm<<<PIX / 64, 256, 0, stream>>>(feat, w0p, b0, G);
  k_mlp<<<(65536 * 4) / 128, 256, 0, stream>>>(G, qtab, cell, wtp,
      w1p, w2p, w3p, w4p32, b1, b2, b3, b4, (float*)d_out);
}

// Round 21
// 155.940 us; speedup vs baseline: 1.0459x; 1.0459x over previous
//
#include <hip/hip_runtime.h>

typedef _Float16 v8h  __attribute__((ext_vector_type(8)));
typedef _Float16 v4h  __attribute__((ext_vector_type(4)));
typedef __fp16   fp16x2 __attribute__((ext_vector_type(2)));
typedef float    v4f  __attribute__((ext_vector_type(4)));
typedef float    v16f __attribute__((ext_vector_type(16)));

#define HH 192
#define WW 192
#define PIX (HH*WW)
#define PITCH 528   // LDS row pitch: 33 x 16B slots, 33 coprime 32 -> conflict-free

// ---------------- ws layout (bytes) ----------------
static const size_t OFF_FEAT  = 0;
static const size_t OFF_G     = 4718592;
static const size_t OFF_QTAB  = 23592960;
static const size_t OFF_W0P   = 27787264;
static const size_t OFF_W1P   = 28082176;
static const size_t OFF_W2P   = 28213248;
static const size_t OFF_W3P   = 28344320;
static const size_t OFF_W4P32 = 28475392;  // 16ks*512 fp16 = 16384 B (R11 pack)
static const size_t OFF_WTP   = 28491776;  // 1024 fp16 = 2048 B

// packed relu->fp16 via builtin (relu in f32, then RTZ pack cvt)
__device__ __forceinline__ unsigned pkrelu(float f0, float f1) {
  union { fp16x2 h; unsigned u; } cv;
  cv.h = __builtin_amdgcn_cvt_pkrtz(fmaxf(f0, 0.f), fmaxf(f1, 0.f));
  return cv.u;
}

// ---------------- prep bodies ----------------
__device__ __forceinline__ void pack16_body(const float* __restrict__ src,
    _Float16* __restrict__ dst, int gid, int K, int N, int KS, int NT, int mode) {
  int total = NT * KS * 512;
  if (gid >= total) return;
  int j  = gid & 7;
  int l  = (gid >> 3) & 63;
  int ks = (gid >> 9) % KS;
  int nt = gid / (512 * KS);
  int k   = ks * 32 + ((l >> 4) << 3) + j;
  int col = nt * 16 + (l & 15);
  float v = 0.f;
  if (col < N && k < K) {
    int row = (mode == 1) ? ((k & 63) * 9 + (k >> 6)) : k;
    v = src[row * N + col];
  }
  dst[gid] = (_Float16)v;
}

__device__ __forceinline__ void pack32_body(const float* __restrict__ src,
                                            _Float16* __restrict__ dst, int gid) {
  int j  = gid & 7;
  int l  = (gid >> 3) & 63;
  int ks = (gid >> 9) & 15;
  int ct = gid >> 13;
  int k = ks * 16 + ((l >> 5) << 3) + j;
  int n = ct * 32 + (l & 31);
  dst[gid] = (_Float16)src[k * 256 + n];
}

// ---------------- fused prep ----------------
// [0,1152) conv 8ch/thread | [1152,1408) qsetup | [1408,1984) w0p |
// [1984,2240) w1p | [2240,2496) w2p | [2496,2752) w3p |
// [2752,2784) w4p32 (permuted rows, cols padded to 32) | [2784,2788) wtp
__global__ __launch_bounds__(256) void k_prep(
    const float* __restrict__ inp, const float* __restrict__ coord,
    const float* __restrict__ enc_w, const float* __restrict__ enc_b,
    const float* __restrict__ w0, const float* __restrict__ w1,
    const float* __restrict__ w2, const float* __restrict__ w3,
    const float* __restrict__ w4,
    _Float16* __restrict__ feat, float4* __restrict__ qtab,
    _Float16* __restrict__ w0p, _Float16* __restrict__ w1p,
    _Float16* __restrict__ w2p, _Float16* __restrict__ w3p,
    _Float16* __restrict__ w4p32, _Float16* __restrict__ wtp) {
  int blk = blockIdx.x, t = threadIdx.x;
  if (blk < 1152) {
    __shared__ float sew[27 * 64];
    __shared__ float seb[64];
    for (int i = t; i < 1728; i += 256) {
      int tap = i >> 6, c = i & 63;
      sew[i] = enc_w[c * 27 + tap];
    }
    if (t < 64) seb[t] = enc_b[t];
    __syncthreads();
    int gid = blk * 256 + t;
    int p = gid >> 3, c8 = (gid & 7) * 8;
    int y = p / WW, x = p - y * WW;
    float a[8];
    #pragma unroll
    for (int j = 0; j < 8; ++j) a[j] = seb[c8 + j];
    #pragma unroll
    for (int ci = 0; ci < 3; ++ci) {
      #pragma unroll
      for (int dy = 0; dy < 3; ++dy) {
        #pragma unroll
        for (int dx = 0; dx < 3; ++dx) {
          int yy = y + dy - 1, xx = x + dx - 1;
          float v = (yy >= 0 && yy < HH && xx >= 0 && xx < WW)
                        ? inp[ci * PIX + yy * WW + xx] : 0.f;
          int tap = ci * 9 + dy * 3 + dx;
          v4f wlo = *(const v4f*)(sew + tap * 64 + c8);
          v4f whi = *(const v4f*)(sew + tap * 64 + c8 + 4);
          a[0] += v * wlo[0]; a[1] += v * wlo[1];
          a[2] += v * wlo[2]; a[3] += v * wlo[3];
          a[4] += v * whi[0]; a[5] += v * whi[1];
          a[6] += v * whi[2]; a[7] += v * whi[3];
        }
      }
    }
    v8h o;
    #pragma unroll
    for (int j = 0; j < 8; ++j) o[j] = (_Float16)a[j];
    *(v8h*)(feat + p * 64 + c8) = o;
  } else if (blk < 1408) {
    int q = (blk - 1152) * 256 + t;
    float cy = coord[q * 2 + 0], cx = coord[q * 2 + 1];
    const float eps = 1e-6f;
    const float rad = (float)(1.0 / 192.0);
    const float CLO = (float)(-1.0 + 1e-6);
    const float CHI = (float)(1.0 - 1e-6);
    const float S2  = (float)(2.0 / 192.0);
    float ry[4], rx[4], ar[4];
    int   li[4];
    #pragma unroll
    for (int k = 0; k < 4; ++k) {
      float oy = (k < 2) ? -rad : rad;
      float ox = (k & 1) ? rad : -rad;
      float cey = __fadd_rn(__fadd_rn(cy, oy), eps);
      float cex = __fadd_rn(__fadd_rn(cx, ox), eps);
      cey = fminf(fmaxf(cey, CLO), CHI);
      cex = fminf(fmaxf(cex, CLO), CHI);
      float ty = __fmul_rn(__fsub_rn(__fmul_rn(__fadd_rn(cey, 1.0f), 192.0f), 1.0f), 0.5f);
      float tx = __fmul_rn(__fsub_rn(__fmul_rn(__fadd_rn(cex, 1.0f), 192.0f), 1.0f), 0.5f);
      float fy = fminf(fmaxf(rintf(ty), 0.f), 191.f);
      float fx = fminf(fmaxf(rintf(tx), 0.f), 191.f);
      float qy = __fsub_rn(__fmul_rn(__fadd_rn(fy, 0.5f), S2), 1.0f);
      float qx = __fsub_rn(__fmul_rn(__fadd_rn(fx, 0.5f), S2), 1.0f);
      ry[k] = __fmul_rn(__fsub_rn(cy, qy), 192.0f);
      rx[k] = __fmul_rn(__fsub_rn(cx, qx), 192.0f);
      ar[k] = fabsf(ry[k] * rx[k]) + 1e-9f;
      li[k] = (int)fy * WW + (int)fx;
    }
    float tot = ar[0] + ar[1] + ar[2] + ar[3];
    #pragma unroll
    for (int k = 0; k < 4; ++k) {
      float wk = ar[3 - k] / tot;
      qtab[q * 4 + k] = make_float4(__int_as_float(li[k]), ry[k], rx[k], wk);
    }
  } else if (blk < 1984) {
    pack16_body(w0, w0p, (blk - 1408) * 256 + t, 576, 256, 18, 16, 1);
  } else if (blk < 2240) {
    pack32_body(w1, w1p, (blk - 1984) * 256 + t);
  } else if (blk < 2496) {
    pack32_body(w2, w2p, (blk - 2240) * 256 + t);
  } else if (blk < 2752) {
    pack32_body(w3, w3p, (blk - 2496) * 256 + t);
  } else if (blk < 2784) {
    // w4p32: 256x3 -> PERMUTED rows (D-fragment order), cols padded to 32
    int gid = (blk - 2752) * 256 + t;       // 0..8191
    int j  = gid & 7;
    int l  = (gid >> 3) & 63;
    int ks = gid >> 9;                      // 0..15
    int k = ks * 16 + ((l >> 5) << 2) + (j & 3) + ((j >> 2) << 3);
    int n = l & 31;
    w4p32[gid] = (n < 3) ? (_Float16)w4[k * 3 + n] : (_Float16)0.f;
  } else {
    int i = (blk - 2784) * 256 + t;
    if (i < 1024) {
      int col = i & 7, j = (i >> 3) & 3, ch = i >> 5;
      wtp[i] = (_Float16)w0[(576 + j) * 256 + ch * 8 + col];
    }
  }
}

// ---------------- G-GEMM (R19 version: M=32, 16x16x32, 4 blocks/CU) --------
__global__ __launch_bounds__(256) void k_ggemm(const _Float16* __restrict__ feat,
    const _Float16* __restrict__ w0p, const float* __restrict__ b0,
    _Float16* __restrict__ G) {
  __shared__ __align__(16) char lds[32 * 1152];
  int t = threadIdx.x, blk = blockIdx.x;
  int lane = t & 63, wv = t >> 6;
  #pragma unroll
  for (int it = 0; it < 9; ++it) {
    int flat = it * 256 + t;
    int r = flat / 72;
    int rem = flat - r * 72;
    int n = rem >> 3, ch = rem & 7;
    int p = blk * 32 + r;
    int y = p / WW, x = p - y * WW;
    int ni = n / 3;
    int yy = y + ni - 1, xx = x + (n - ni * 3) - 1;
    v8h v = {};
    if (yy >= 0 && yy < HH && xx >= 0 && xx < WW)
      v = *(const v8h*)(feat + (yy * WW + xx) * 64 + ch * 8);
    int byte = r * 1152 + n * 128 + ch * 16;
    byte ^= (r & 7) << 4;
    *(v8h*)(lds + byte) = v;
  }
  __syncthreads();
  v4f acc[4][2] = {};
  for (int ks = 0; ks < 18; ++ks) {
    v8h bfr[2], afr[4];
    #pragma unroll
    for (int mt = 0; mt < 2; ++mt) {
      int row = mt * 16 + (lane & 15);
      int byte = row * 1152 + ks * 64 + (lane >> 4) * 16;
      byte ^= (row & 7) << 4;
      bfr[mt] = *(const v8h*)(lds + byte);
    }
    #pragma unroll
    for (int nt = 0; nt < 4; ++nt)
      afr[nt] = *(const v8h*)(w0p + (((wv * 4 + nt) * 18 + ks) * 64 + lane) * 8);
    #pragma unroll
    for (int nt = 0; nt < 4; ++nt)
      #pragma unroll
      for (int mt = 0; mt < 2; ++mt)
        acc[nt][mt] = __builtin_amdgcn_mfma_f32_16x16x32_f16(afr[nt], bfr[mt], acc[nt][mt], 0, 0, 0);
  }
  __syncthreads();
  #pragma unroll
  for (int nt = 0; nt < 4; ++nt) {
    int n0 = (wv * 4 + nt) * 16 + (lane >> 4) * 4;
    float4 bb = *(const float4*)(b0 + n0);
    #pragma unroll
    for (int mt = 0; mt < 2; ++mt) {
      int m = mt * 16 + (lane & 15);
      v4f a = acc[nt][mt];
      v4h h;
      h[0] = (_Float16)(a[0] + bb.x);
      h[1] = (_Float16)(a[1] + bb.y);
      h[2] = (_Float16)(a[2] + bb.z);
      h[3] = (_Float16)(a[3] + bb.w);
      int byte = m * 512 + n0 * 2;
      byte ^= (m & 7) << 4;
      *(v4h*)(lds + byte) = h;
    }
  }
  __syncthreads();
  #pragma unroll
  for (int i = 0; i < 4; ++i) {
    int ci = i * 256 + t;
    int m = ci >> 5, sl = ci & 31;
    int byte = m * 512 + sl * 16;
    byte ^= (m & 7) << 4;
    v8h v = *(const v8h*)(lds + byte);
    *(v8h*)(G + (size_t)(blk * 32 + m) * 256 + sl * 8) = v;
  }
}

// ------- hidden layer (256->256), relu, single buffer, 32x32x16 -------
__device__ __forceinline__ void layer256w(char* buf,
    const _Float16* __restrict__ wp, const float* __restrict__ bias,
    int lane, int wv) {
  int sl = lane & 31;
  int kg = lane >> 5;
  v16f acc[4][2];
  #pragma unroll
  for (int c = 0; c < 2; ++c) {
    #pragma unroll
    for (int q = 0; q < 4; ++q) {
      float4 bb = *(const float4*)(bias + wv * 64 + c * 32 + q * 8 + kg * 4);
      #pragma unroll
      for (int st = 0; st < 4; ++st) {
        acc[st][c][q * 4 + 0] = bb.x;
        acc[st][c][q * 4 + 1] = bb.y;
        acc[st][c][q * 4 + 2] = bb.z;
        acc[st][c][q * 4 + 3] = bb.w;
      }
    }
  }
  const _Float16* wbase = wp + (size_t)(wv * 2) * 16 * 512 + lane * 8;
  const char* bbase = buf + sl * PITCH + kg * 16;
  #pragma unroll
  for (int ks = 0; ks < 16; ++ks) {
    v8h afr[2], bfr[4];
    afr[0] = *(const v8h*)(wbase + ks * 512);
    afr[1] = *(const v8h*)(wbase + (16 + ks) * 512);
    #pragma unroll
    for (int st = 0; st < 4; ++st)
      bfr[st] = *(const v8h*)(bbase + st * (32 * PITCH) + ks * 32);
    #pragma unroll
    for (int st = 0; st < 4; ++st)
      #pragma unroll
      for (int c = 0; c < 2; ++c)
        acc[st][c] = __builtin_amdgcn_mfma_f32_32x32x16_f16(afr[c], bfr[st], acc[st][c], 0, 0, 0);
  }
  __syncthreads();
  // D layout (32x32): col=lane&31 (sample), row=(reg&3)+8*(reg>>2)+4*(lane>>5)
  #pragma unroll
  for (int c = 0; c < 2; ++c) {
    #pragma unroll
    for (int q = 0; q < 4; ++q) {
      int n0 = wv * 64 + c * 32 + q * 8 + kg * 4;
      #pragma unroll
      for (int st = 0; st < 4; ++st) {
        int s = st * 32 + sl;
        uint2 hv;
        hv.x = pkrelu(acc[st][c][q * 4 + 0], acc[st][c][q * 4 + 1]);
        hv.y = pkrelu(acc[st][c][q * 4 + 2], acc[st][c][q * 4 + 3]);
        *(uint2*)(buf + s * PITCH + n0 * 2) = hv;
      }
    }
  }
  __syncthreads();
}

// ------- layer 3 + fused L4: acc feeds L4's B-operand directly -------
__device__ __forceinline__ void layer3_fused(char* buf,
    const _Float16* __restrict__ wp, const float* __restrict__ bias,
    const _Float16* __restrict__ w4p32, const float* __restrict__ b4,
    const float4* __restrict__ qtab, float* __restrict__ out,
    int lane, int wv, int blk, int t) {
  int sl = lane & 31;
  int kg = lane >> 5;
  v16f acc[4][2];
  #pragma unroll
  for (int c = 0; c < 2; ++c) {
    #pragma unroll
    for (int q = 0; q < 4; ++q) {
      float4 bb = *(const float4*)(bias + wv * 64 + c * 32 + q * 8 + kg * 4);
      #pragma unroll
      for (int st = 0; st < 4; ++st) {
        acc[st][c][q * 4 + 0] = bb.x;
        acc[st][c][q * 4 + 1] = bb.y;
        acc[st][c][q * 4 + 2] = bb.z;
        acc[st][c][q * 4 + 3] = bb.w;
      }
    }
  }
  const _Float16* wbase = wp + (size_t)(wv * 2) * 16 * 512 + lane * 8;
  const char* bbase = buf + sl * PITCH + kg * 16;
  #pragma unroll
  for (int ks = 0; ks < 16; ++ks) {
    v8h afr[2], bfr[4];
    afr[0] = *(const v8h*)(wbase + ks * 512);
    afr[1] = *(const v8h*)(wbase + (16 + ks) * 512);
    #pragma unroll
    for (int st = 0; st < 4; ++st)
      bfr[st] = *(const v8h*)(bbase + st * (32 * PITCH) + ks * 32);
    #pragma unroll
    for (int st = 0; st < 4; ++st)
      #pragma unroll
      for (int c = 0; c < 2; ++c)
        acc[st][c] = __builtin_amdgcn_mfma_f32_32x32x16_f16(afr[c], bfr[st], acc[st][c], 0, 0, 0);
  }
  __syncthreads();   // all reads of buf done -> buf reusable for partials
  float4* pb = (float4*)buf;
  #pragma unroll
  for (int st = 0; st < 4; ++st) {
    v16f a4 = {};
    #pragma unroll
    for (int ksl = 0; ksl < 4; ++ksl) {
      const v16f& a = acc[st][ksl >> 1];
      int base = 8 * (ksl & 1);
      union { unsigned u[4]; v8h h; } bb;
      bb.u[0] = pkrelu(a[base + 0], a[base + 1]);
      bb.u[1] = pkrelu(a[base + 2], a[base + 3]);
      bb.u[2] = pkrelu(a[base + 4], a[base + 5]);
      bb.u[3] = pkrelu(a[base + 6], a[base + 7]);
      v8h afr = *(const v8h*)(w4p32 + (size_t)(wv * 4 + ksl) * 512 + lane * 8);
      a4 = __builtin_amdgcn_mfma_f32_32x32x16_f16(afr, bb.h, a4, 0, 0, 0);
    }
    if (kg == 0) {
      pb[wv * 128 + st * 32 + sl] = make_float4(a4[0], a4[1], a4[2], 0.f);
    }
  }
  __syncthreads();
  if (t < 96) {
    int ql = t / 3, ch = t - ql * 3;
    float bch = b4[ch];
    float sum = 0.f;
    #pragma unroll
    for (int k = 0; k < 4; ++k) {
      int s_local = ql * 4 + k;
      float wk = qtab[blk * 128 + s_local].w;
      float pred = bch;
      #pragma unroll
      for (int w = 0; w < 4; ++w)
        pred += ((const float*)&pb[w * 128 + s_local])[ch];
      sum += wk * pred;
    }
    out[(blk * 32 + ql) * 3 + ch] = sum;
  }
}

// ---------------- fused MLP over 128 samples/block -------------
__global__ __launch_bounds__(256, 2) void k_mlp(
    const _Float16* __restrict__ G, const float4* __restrict__ qtab,
    const float* __restrict__ cell, const _Float16* __restrict__ wtp,
    const _Float16* __restrict__ w1p, const _Float16* __restrict__ w2p,
    const _Float16* __restrict__ w3p, const _Float16* __restrict__ w4p32,
    const float* __restrict__ b1, const float* __restrict__ b2,
    const float* __restrict__ b3, const float* __restrict__ b4,
    float* __restrict__ out) {
  __shared__ __align__(16) char buf[128 * PITCH];
  int t = threadIdx.x, blk = blockIdx.x;
  int lane = t & 63, wv = t >> 6;
  // ---- phase 0: h1 = relu(G[pix] + tail-terms) -> buf ----
  {
    int ch = t & 31;
    int r8 = t >> 5;
    const _Float16* wtb = wtp + ch * 32;
    v8h wt0 = *(const v8h*)(wtb);
    v8h wt1 = *(const v8h*)(wtb + 8);
    v8h wt2 = *(const v8h*)(wtb + 16);
    v8h wt3 = *(const v8h*)(wtb + 24);
    #pragma unroll
    for (int g = 0; g < 16; ++g) {
      int r = g * 8 + r8;
      int s = blk * 128 + r;
      float4 qe = qtab[s];
      int lin = __float_as_int(qe.x);
      float rel0 = qe.y, rel1 = qe.z;
      int q = s >> 2;
      float rc0 = cell[q * 2 + 0] * 192.f, rc1 = cell[q * 2 + 1] * 192.f;
      v8h gv = *(const v8h*)(G + (size_t)lin * 256 + ch * 8);
      float vv[8];
      #pragma unroll
      for (int i = 0; i < 8; ++i)
        vv[i] = (float)gv[i] + rel0 * (float)wt0[i] + rel1 * (float)wt1[i]
              + rc0 * (float)wt2[i] + rc1 * (float)wt3[i];
      uint4 hv;
      hv.x = pkrelu(vv[0], vv[1]);
      hv.y = pkrelu(vv[2], vv[3]);
      hv.z = pkrelu(vv[4], vv[5]);
      hv.w = pkrelu(vv[6], vv[7]);
      *(uint4*)(buf + r * PITCH + ch * 16) = hv;
    }
  }
  __syncthreads();
  layer256w(buf, w1p, b1, lane, wv);
  layer256w(buf, w2p, b2, lane, wv);
  layer3_fused(buf, w3p, b3, w4p32, b4, qtab, out, lane, wv, blk, t);
}

extern "C" void kernel_launch(void* const* d_in, const int* in_sizes, int n_in,
                              void* d_out, int out_size, void* d_ws, size_t ws_size,
                              hipStream_t stream) {
  const float* inp   = (const float*)d_in[0];
  const float* coord = (const float*)d_in[1];
  const float* cell  = (const float*)d_in[2];
  const float* enc_w = (const float*)d_in[3];
  const float* enc_b = (const float*)d_in[4];
  const float* w0 = (const float*)d_in[5];
  const float* b0 = (const float*)d_in[6];
  const float* w1 = (const float*)d_in[7];
  const float* b1 = (const float*)d_in[8];
  const float* w2 = (const float*)d_in[9];
  const float* b2 = (const float*)d_in[10];
  const float* w3 = (const float*)d_in[11];
  const float* b3 = (const float*)d_in[12];
  const float* w4 = (const float*)d_in[13];
  const float* b4 = (const float*)d_in[14];
  char* ws = (char*)d_ws;
  _Float16* feat  = (_Float16*)(ws + OFF_FEAT);
  _Float16* G     = (_Float16*)(ws + OFF_G);
  float4*   qtab  = (float4*)(ws + OFF_QTAB);
  _Float16* w0p   = (_Float16*)(ws + OFF_W0P);
  _Float16* w1p   = (_Float16*)(ws + OFF_W1P);
  _Float16* w2p   = (_Float16*)(ws + OFF_W2P);
  _Float16* w3p   = (_Float16*)(ws + OFF_W3P);
  _Float16* w4p32 = (_Float16*)(ws + OFF_W4P32);
  _Float16* wtp   = (_Float16*)(ws + OFF_WTP);

  k_prep<<<2788, 256, 0, stream>>>(inp, coord, enc_w, enc_b, w0, w1, w2, w3, w4,
                                   feat, qtab, w0p, w1p, w2p, w3p, w4p32, wtp);
  k_ggemm<<<PIX / 32, 256, 0, stream>>>(feat, w0p, b0, G);
  k_mlp<<<(65536 * 4) / 128, 256, 0, stream>>>(G, qtab, cell, wtp,
      w1p, w2p, w3p, w4p32, b1, b2, b3, b4, (float*)d_out);
}